// Round 1
// baseline (500.424 us; speedup 1.0000x reference)
//
#include <hip/hip_runtime.h>
#include <stdint.h>
#include <stddef.h>

// FastChannelAttention on MI355X.
// Decomposition:
//   K0a: zero ssq accumulators (atomics target, must be zeroed every call)
//   K0b: swizzle qkv_w fp32 -> bf16 wl[(c/8)*1536 + j][8]   (MFMA-B-friendly)
//   K1 : qkv = x @ qkv_w   (bf16 MFMA, 128x128 tile, K=512), stores bf16 qkv
//   K2 : S[b,h] = Q^T K (64x64 Gram over N) + sum-of-squares (norms)
//   K3 : attn = softmax(S/(|q||k|) * temp);  M_b = blockdiag(attn)^T @ proj_w
//   K4 : out = V @ M_b + proj_b  (bf16 MFMA, fp32 out)

typedef unsigned short u16;
typedef __attribute__((ext_vector_type(8))) unsigned short u16x8;
typedef __attribute__((ext_vector_type(8))) __bf16 bf16x8;
typedef __attribute__((ext_vector_type(4))) float f32x4;

#define B_DIM 4
#define N_TOK 16384
#define C_DIM 512
#define H_DIM 8
#define CQ3   1536
#define NROWS 65536

__device__ __forceinline__ u16 f2bf(float f) {              // RNE fp32->bf16
  union { float f; uint32_t u; } v; v.f = f;
  uint32_t r = v.u + 0x7FFFu + ((v.u >> 16) & 1u);
  return (u16)(r >> 16);
}
__device__ __forceinline__ float bf2f(u16 u) {
  union { uint32_t u; float f; } v; v.u = ((uint32_t)u) << 16;
  return v.f;
}
__device__ __forceinline__ bf16x8 as_bf16x8(u16x8 u) {
  union { u16x8 u; bf16x8 b; } v; v.u = u; return v.b;
}

// ---------------- K0a: zero ----------------
__global__ void k_zero(float* p, int n) {
  int i = blockIdx.x * 256 + threadIdx.x;
  if (i < n) p[i] = 0.f;
}

// ---------------- K0b: weight swizzle fp32 -> bf16 [(c/8)*1536 + j][8] ----------------
__global__ __launch_bounds__(256) void k_wswz(const float* __restrict__ w, u16* __restrict__ wl) {
  int g = blockIdx.x * 256 + threadIdx.x;       // 0..98303 slots
  int c8 = g / CQ3, j = g - c8 * CQ3;
  u16x8 o;
#pragma unroll
  for (int i = 0; i < 8; ++i) o[i] = f2bf(w[(size_t)(c8 * 8 + i) * CQ3 + j]);
  *(u16x8*)(wl + (size_t)g * 8) = o;
}

// ---------------- K1: QKV GEMM (M=65536, N=1536, K=512) ----------------
// LDS layouts: As/Bs [kblk(8)][idx(128)][8] bf16  (16B slots; conflict-free b128 reads)
__global__ __launch_bounds__(256) void k_qkv(const float* __restrict__ x,
                                             const u16* __restrict__ wl,
                                             u16* __restrict__ qkv) {
  __shared__ __align__(16) u16 As[8192];
  __shared__ __align__(16) u16 Bs[8192];
  const int tid = threadIdx.x, lane = tid & 63;
  const int wid = tid >> 6;
  const int cb = blockIdx.x, rb = blockIdx.y;
  const int row0 = rb * 128, col0 = cb * 128;
  const int wr = wid >> 1, wc = wid & 1;
  f32x4 acc[4][4];
#pragma unroll
  for (int i = 0; i < 4; ++i)
#pragma unroll
    for (int j = 0; j < 4; ++j) acc[i][j] = (f32x4){0.f, 0.f, 0.f, 0.f};

  for (int kb = 0; kb < 8; ++kb) {
    // A: x fp32 -> bf16, slot = kblk*128 + m, 8 consecutive k per slot
#pragma unroll
    for (int s4 = 0; s4 < 4; ++s4) {
      int slot = s4 * 256 + tid;
      int kblk = slot >> 7, m = slot & 127;
      const float* g = x + (size_t)(row0 + m) * C_DIM + kb * 64 + kblk * 8;
      float4 v0 = *(const float4*)g;
      float4 v1 = *(const float4*)(g + 4);
      u16x8 o;
      o[0] = f2bf(v0.x); o[1] = f2bf(v0.y); o[2] = f2bf(v0.z); o[3] = f2bf(v0.w);
      o[4] = f2bf(v1.x); o[5] = f2bf(v1.y); o[6] = f2bf(v1.z); o[7] = f2bf(v1.w);
      *(u16x8*)&As[slot * 8] = o;
    }
    // B: pre-swizzled bf16 weights, coalesced 16B loads
#pragma unroll
    for (int s4 = 0; s4 < 4; ++s4) {
      int slot = s4 * 256 + tid;
      int kblk = slot >> 7, n = slot & 127;
      const u16* g = wl + ((size_t)(kb * 8 + kblk) * CQ3 + col0 + n) * 8;
      *(u16x8*)&Bs[slot * 8] = *(const u16x8*)g;
    }
    __syncthreads();
#pragma unroll
    for (int kk = 0; kk < 2; ++kk) {
      const int krow = kk * 4 + (lane >> 4);
      bf16x8 af[4], bfr[4];
#pragma unroll
      for (int t = 0; t < 4; ++t)
        af[t] = *(const bf16x8*)&As[(krow * 128 + wr * 64 + t * 16 + (lane & 15)) * 8];
#pragma unroll
      for (int t = 0; t < 4; ++t)
        bfr[t] = *(const bf16x8*)&Bs[(krow * 128 + wc * 64 + t * 16 + (lane & 15)) * 8];
#pragma unroll
      for (int mt = 0; mt < 4; ++mt)
#pragma unroll
        for (int nt = 0; nt < 4; ++nt)
          acc[mt][nt] = __builtin_amdgcn_mfma_f32_16x16x32_bf16(af[mt], bfr[nt], acc[mt][nt], 0, 0, 0);
    }
    __syncthreads();
  }
  // epilogue: bf16 store. C/D layout: col = lane&15, row = (lane>>4)*4 + r
#pragma unroll
  for (int mt = 0; mt < 4; ++mt)
#pragma unroll
    for (int nt = 0; nt < 4; ++nt) {
      int col = col0 + wc * 64 + nt * 16 + (lane & 15);
#pragma unroll
      for (int r = 0; r < 4; ++r) {
        int row = row0 + wr * 64 + mt * 16 + (lane >> 4) * 4 + r;
        qkv[(size_t)row * CQ3 + col] = f2bf(acc[mt][nt][r]);
      }
    }
}

// ---------------- K2: Gram S[b,h] = Q^T K + sumsq (norms) ----------------
// grid (16 nblk, 32 bh), 256 thr = 4 waves, wave-private transpose staging.
__global__ __launch_bounds__(256) void k_gram(const u16* __restrict__ qkv,
                                              float* __restrict__ Sp,
                                              float* __restrict__ ssq) {
  __shared__ __align__(16) u16 Qs[4][2048];   // [wave][nb2(4)][d(64)][8] bf16
  __shared__ __align__(16) u16 Ks[4][2048];
  __shared__ float Ssh[4096];
  __shared__ float ssqsh[128];
  const int tid = threadIdx.x, lane = tid & 63, wid = tid >> 6;
  const int nblk = blockIdx.x, bh = blockIdx.y;
  const int b = bh >> 3, hh = bh & 7;
  for (int i = tid; i < 4096; i += 256) Ssh[i] = 0.f;
  if (tid < 128) ssqsh[tid] = 0.f;
  __syncthreads();

  f32x4 acc[4][4];
#pragma unroll
  for (int i = 0; i < 4; ++i)
#pragma unroll
    for (int j = 0; j < 4; ++j) acc[i][j] = (f32x4){0.f, 0.f, 0.f, 0.f};
  float sq[8], sk[8];
#pragma unroll
  for (int i = 0; i < 8; ++i) { sq[i] = 0.f; sk[i] = 0.f; }

  const size_t rowbase = (size_t)b * N_TOK + (size_t)nblk * 1024 + wid * 256;
  const int colq = hh * 64;

  for (int it = 0; it < 8; ++it) {
#pragma unroll
    for (int j4 = 0; j4 < 4; ++j4) {
      int idx = j4 * 64 + lane;
      int n = idx >> 3;
      int dd0 = (idx & 7) * 8;              // == (lane&7)*8, fixed per lane
      const u16* gq = qkv + (rowbase + it * 32 + n) * CQ3 + colq + dd0;
      u16x8 q8 = *(const u16x8*)gq;
      u16x8 k8 = *(const u16x8*)(gq + C_DIM);
#pragma unroll
      for (int i = 0; i < 8; ++i) {
        float qf = bf2f(q8[i]); sq[i] += qf * qf;
        float kf = bf2f(k8[i]); sk[i] += kf * kf;
      }
      int base = ((n >> 3) * 64 + dd0) * 8 + (n & 7);   // transposed [nb2][d][nin]
#pragma unroll
      for (int i = 0; i < 8; ++i) {
        Qs[wid][base + i * 8] = q8[i];
        Ks[wid][base + i * 8] = k8[i];
      }
    }
    const int krow = lane >> 4;
    bf16x8 aq[4], ak[4];
#pragma unroll
    for (int m = 0; m < 4; ++m) {
      aq[m] = *(const bf16x8*)&Qs[wid][(krow * 64 + m * 16 + (lane & 15)) * 8];
      ak[m] = *(const bf16x8*)&Ks[wid][(krow * 64 + m * 16 + (lane & 15)) * 8];
    }
#pragma unroll
    for (int dm = 0; dm < 4; ++dm)
#pragma unroll
      for (int em = 0; em < 4; ++em)
        acc[dm][em] = __builtin_amdgcn_mfma_f32_16x16x32_bf16(aq[dm], ak[em], acc[dm][em], 0, 0, 0);
  }
  // reduce wave partials into Ssh
#pragma unroll
  for (int dm = 0; dm < 4; ++dm)
#pragma unroll
    for (int em = 0; em < 4; ++em)
#pragma unroll
      for (int r = 0; r < 4; ++r)
        atomicAdd(&Ssh[(dm * 16 + (lane >> 4) * 4 + r) * 64 + em * 16 + (lane & 15)], acc[dm][em][r]);
#pragma unroll
  for (int i = 0; i < 8; ++i) {
    atomicAdd(&ssqsh[(lane & 7) * 8 + i], sq[i]);
    atomicAdd(&ssqsh[64 + (lane & 7) * 8 + i], sk[i]);
  }
  __syncthreads();
  float* sp = Sp + ((size_t)bh * 16 + nblk) * 4096;
  for (int i = tid; i < 4096; i += 256) sp[i] = Ssh[i];
  if (tid < 128) {
    int c = tid & 63;
    int off = (tid < 64) ? (colq + c) : (C_DIM + colq + c);
    atomicAdd(&ssq[b * 1024 + off], ssqsh[tid]);
  }
}

// ---------------- K3: softmax + fold into proj: M_b[c'=h*64+e][j] ----------------
__global__ __launch_bounds__(256) void k_attn_m(const float* __restrict__ Sp,
                                                const float* __restrict__ ssq,
                                                const float* __restrict__ temp,
                                                const float* __restrict__ pw,
                                                u16* __restrict__ Ml) {
  __shared__ float Ssh[4096];
  __shared__ float rq[64], rk[64];
  const int tid = threadIdx.x, lane = tid & 63, wid = tid >> 6;
  const int bh = blockIdx.x, b = bh >> 3, hh = bh & 7;
#pragma unroll
  for (int t2 = 0; t2 < 16; ++t2) {
    int idx = t2 * 256 + tid;
    float s = 0.f;
#pragma unroll
    for (int p = 0; p < 16; ++p) s += Sp[((size_t)bh * 16 + p) * 4096 + idx];
    Ssh[idx] = s;
  }
  if (tid < 64)
    rq[tid] = 1.f / fmaxf(sqrtf(ssq[b * 1024 + hh * 64 + tid]), 1e-12f);
  else if (tid < 128)
    rk[tid - 64] = 1.f / fmaxf(sqrtf(ssq[b * 1024 + C_DIM + hh * 64 + (tid - 64)]), 1e-12f);
  __syncthreads();
  const float tp = temp[hh];
  const int d = tid >> 2, q4 = tid & 3;       // row d, 16 cols per thread
  float vals[16];
  float mx = -3.0e38f;
  const float rqd = rq[d];
#pragma unroll
  for (int i = 0; i < 16; ++i) {
    float v = Ssh[d * 64 + q4 * 16 + i] * rqd * rk[q4 * 16 + i] * tp;
    vals[i] = v; mx = fmaxf(mx, v);
  }
  mx = fmaxf(mx, __shfl_xor(mx, 1));
  mx = fmaxf(mx, __shfl_xor(mx, 2));
  float sum = 0.f;
#pragma unroll
  for (int i = 0; i < 16; ++i) { vals[i] = __expf(vals[i] - mx); sum += vals[i]; }
  sum += __shfl_xor(sum, 1);
  sum += __shfl_xor(sum, 2);
  const float inv = 1.f / sum;
#pragma unroll
  for (int i = 0; i < 16; ++i) Ssh[d * 64 + q4 * 16 + i] = vals[i] * inv;   // A in place
  __syncthreads();
  // M[e][j] = sum_d A[d][e] * pw[hh*64+d][j];  wave owns j-range wid*128..+128
  f32x4 macc[4][8];
#pragma unroll
  for (int i = 0; i < 4; ++i)
#pragma unroll
    for (int j = 0; j < 8; ++j) macc[i][j] = (f32x4){0.f, 0.f, 0.f, 0.f};
#pragma unroll
  for (int kk = 0; kk < 2; ++kk) {
    bf16x8 af[4], bfr[8];
#pragma unroll
    for (int em = 0; em < 4; ++em) {
      u16x8 t8;
#pragma unroll
      for (int i = 0; i < 8; ++i) {
        int dd = kk * 32 + (lane >> 4) * 8 + i;
        t8[i] = f2bf(Ssh[dd * 64 + em * 16 + (lane & 15)]);
      }
      af[em] = as_bf16x8(t8);
    }
#pragma unroll
    for (int nt = 0; nt < 8; ++nt) {
      int j = wid * 128 + nt * 16 + (lane & 15);
      u16x8 t8;
#pragma unroll
      for (int i = 0; i < 8; ++i) {
        int dd = kk * 32 + (lane >> 4) * 8 + i;
        t8[i] = f2bf(pw[(size_t)(hh * 64 + dd) * C_DIM + j]);
      }
      bfr[nt] = as_bf16x8(t8);
    }
#pragma unroll
    for (int em = 0; em < 4; ++em)
#pragma unroll
      for (int nt = 0; nt < 8; ++nt)
        macc[em][nt] = __builtin_amdgcn_mfma_f32_16x16x32_bf16(af[em], bfr[nt], macc[em][nt], 0, 0, 0);
  }
#pragma unroll
  for (int em = 0; em < 4; ++em)
#pragma unroll
    for (int nt = 0; nt < 8; ++nt) {
      int j = wid * 128 + nt * 16 + (lane & 15);
#pragma unroll
      for (int r = 0; r < 4; ++r) {
        int e = em * 16 + (lane >> 4) * 4 + r;
        int cp = hh * 64 + e;
        Ml[(size_t)b * 262144 + ((size_t)(cp >> 3) * C_DIM + j) * 8 + (cp & 7)] = f2bf(macc[em][nt][r]);
      }
    }
}

// ---------------- K4: out = V @ M_b + bias (fp32 out) ----------------
__global__ __launch_bounds__(256) void k_out(const u16* __restrict__ qkv,
                                             const u16* __restrict__ Ml,
                                             const float* __restrict__ pb,
                                             float* __restrict__ out) {
  __shared__ __align__(16) u16 As[8192];
  __shared__ __align__(16) u16 Bs[8192];
  const int tid = threadIdx.x, lane = tid & 63, wid = tid >> 6;
  const int cb = blockIdx.x, rb = blockIdx.y, b = blockIdx.z;
  const int row0 = rb * 128, col0 = cb * 128;
  const int wr = wid >> 1, wc = wid & 1;
  f32x4 acc[4][4];
#pragma unroll
  for (int i = 0; i < 4; ++i)
#pragma unroll
    for (int j = 0; j < 4; ++j) acc[i][j] = (f32x4){0.f, 0.f, 0.f, 0.f};
  const u16* vbase = qkv + (size_t)b * N_TOK * CQ3 + 1024;   // V columns
  const u16* mbase = Ml + (size_t)b * 262144;

  for (int kb = 0; kb < 8; ++kb) {
#pragma unroll
    for (int s4 = 0; s4 < 4; ++s4) {
      int slot = s4 * 256 + tid;
      int kblk = slot >> 7, m = slot & 127;
      *(u16x8*)&As[slot * 8] =
          *(const u16x8*)(vbase + (size_t)(row0 + m) * CQ3 + kb * 64 + kblk * 8);
    }
#pragma unroll
    for (int s4 = 0; s4 < 4; ++s4) {
      int slot = s4 * 256 + tid;
      int kblk = slot >> 7, n = slot & 127;
      *(u16x8*)&Bs[slot * 8] =
          *(const u16x8*)(mbase + ((size_t)(kb * 8 + kblk) * C_DIM + col0 + n) * 8);
    }
    __syncthreads();
#pragma unroll
    for (int kk = 0; kk < 2; ++kk) {
      const int krow = kk * 4 + (lane >> 4);
      bf16x8 af[4], bfr[4];
#pragma unroll
      for (int t = 0; t < 4; ++t)
        af[t] = *(const bf16x8*)&As[(krow * 128 + wr * 64 + t * 16 + (lane & 15)) * 8];
#pragma unroll
      for (int t = 0; t < 4; ++t)
        bfr[t] = *(const bf16x8*)&Bs[(krow * 128 + wc * 64 + t * 16 + (lane & 15)) * 8];
#pragma unroll
      for (int mt = 0; mt < 4; ++mt)
#pragma unroll
        for (int nt = 0; nt < 4; ++nt)
          acc[mt][nt] = __builtin_amdgcn_mfma_f32_16x16x32_bf16(af[mt], bfr[nt], acc[mt][nt], 0, 0, 0);
    }
    __syncthreads();
  }
#pragma unroll
  for (int nt = 0; nt < 4; ++nt) {
    int col = col0 + wc * 64 + nt * 16 + (lane & 15);
    float bias = pb[col];
#pragma unroll
    for (int mt = 0; mt < 4; ++mt)
#pragma unroll
      for (int r = 0; r < 4; ++r) {
        int row = row0 + wr * 64 + mt * 16 + (lane >> 4) * 4 + r;
        out[((size_t)b * N_TOK + row) * C_DIM + col] = acc[mt][nt][r] + bias;
      }
  }
}

extern "C" void kernel_launch(void* const* d_in, const int* in_sizes, int n_in,
                              void* d_out, int out_size, void* d_ws, size_t ws_size,
                              hipStream_t stream) {
  const float* x      = (const float*)d_in[0];
  // d_in[1]=H, d_in[2]=W (unused)
  const float* qkv_w  = (const float*)d_in[3];
  const float* proj_w = (const float*)d_in[4];
  const float* proj_b = (const float*)d_in[5];
  const float* temp   = (const float*)d_in[6];
  float* out = (float*)d_out;

  char* ws = (char*)d_ws;
  const size_t QKV_B = (size_t)NROWS * CQ3 * 2;        // 201326592
  const size_t WL_B  = (size_t)C_DIM * CQ3 * 2;        // 1572864
  const size_t SP_B  = (size_t)32 * 16 * 4096 * 4;     // 8388608
  const size_t SSQ_B = (size_t)4096 * 4;               // 16384
  u16*   qkv = (u16*)ws;
  u16*   wl  = (u16*)(ws + QKV_B);
  float* Sp  = (float*)(ws + QKV_B + WL_B);
  float* ssq = (float*)(ws + QKV_B + WL_B + SP_B);
  u16*   Ml  = (u16*)(ws + QKV_B + WL_B + SP_B + SSQ_B);

  k_zero<<<16, 256, 0, stream>>>(ssq, 4096);
  k_wswz<<<384, 256, 0, stream>>>(qkv_w, wl);
  k_qkv<<<dim3(12, 512), 256, 0, stream>>>(x, wl, qkv);
  k_gram<<<dim3(16, 32), 256, 0, stream>>>(qkv, Sp, ssq);
  k_attn_m<<<32, 256, 0, stream>>>(Sp, ssq, temp, proj_w, Ml);
  k_out<<<dim3(4, 128, 4), 256, 0, stream>>>(qkv, Ml, proj_b, out);
}

// Round 2
// 396.045 us; speedup vs baseline: 1.2636x; 1.2636x over previous
//
#include <hip/hip_runtime.h>
#include <stdint.h>
#include <stddef.h>

// FastChannelAttention on MI355X.
//   K0a: zero ssq accumulators
//   K0b: swizzle qkv_w fp32 -> bf16 wl[(c/8)*1536 + j][8]
//   Kxb: x fp32 -> bf16 (row-major), once
//   K1 : qkv = xb @ wl   (bf16 MFMA 128x128, global_load_lds staging, XCD swizzle)
//   K2 : S[b,h] = Q^T K (64x64 Gram over N) + sum-of-squares
//   K3 : attn = softmax(S/(|q||k|) * temp);  M_b = blockdiag(attn)^T @ proj_w
//   K4 : out = V @ M_b + proj_b  (global_load_lds staging, XCD swizzle)

typedef unsigned short u16;
typedef __attribute__((ext_vector_type(8))) unsigned short u16x8;
typedef __attribute__((ext_vector_type(8))) __bf16 bf16x8;
typedef __attribute__((ext_vector_type(4))) float f32x4;

#define B_DIM 4
#define N_TOK 16384
#define C_DIM 512
#define H_DIM 8
#define CQ3   1536
#define NROWS 65536

__device__ __forceinline__ u16 f2bf(float f) {              // RNE fp32->bf16
  union { float f; uint32_t u; } v; v.f = f;
  uint32_t r = v.u + 0x7FFFu + ((v.u >> 16) & 1u);
  return (u16)(r >> 16);
}
__device__ __forceinline__ float bf2f(u16 u) {
  union { uint32_t u; float f; } v; v.u = ((uint32_t)u) << 16;
  return v.f;
}
__device__ __forceinline__ bf16x8 as_bf16x8(u16x8 u) {
  union { u16x8 u; bf16x8 b; } v; v.u = u; return v.b;
}
__device__ __forceinline__ void gl_lds16(const void* g, void* l) {
  __builtin_amdgcn_global_load_lds(
      (const __attribute__((address_space(1))) uint32_t*)g,
      (__attribute__((address_space(3))) uint32_t*)l, 16, 0, 0);
}

// ---------------- K0a: zero ----------------
__global__ void k_zero(float* p, int n) {
  int i = blockIdx.x * 256 + threadIdx.x;
  if (i < n) p[i] = 0.f;
}

// ---------------- K0b: weight swizzle fp32 -> bf16 [(c/8)*1536 + j][8] ----------------
__global__ __launch_bounds__(256) void k_wswz(const float* __restrict__ w, u16* __restrict__ wl) {
  int g = blockIdx.x * 256 + threadIdx.x;       // 0..98303 slots
  int c8 = g / CQ3, j = g - c8 * CQ3;
  u16x8 o;
#pragma unroll
  for (int i = 0; i < 8; ++i) o[i] = f2bf(w[(size_t)(c8 * 8 + i) * CQ3 + j]);
  *(u16x8*)(wl + (size_t)g * 8) = o;
}

// ---------------- Kxb: x fp32 -> bf16 row-major ----------------
__global__ __launch_bounds__(256) void k_xb(const float* __restrict__ x, u16* __restrict__ xb) {
  const int nchunk = NROWS * C_DIM / 8;          // 4194304
  const int stride = 2048 * 256;
  for (int i = blockIdx.x * 256 + threadIdx.x; i < nchunk; i += stride) {
    float4 v0 = *(const float4*)(x + (size_t)i * 8);
    float4 v1 = *(const float4*)(x + (size_t)i * 8 + 4);
    u16x8 o;
    o[0] = f2bf(v0.x); o[1] = f2bf(v0.y); o[2] = f2bf(v0.z); o[3] = f2bf(v0.w);
    o[4] = f2bf(v1.x); o[5] = f2bf(v1.y); o[6] = f2bf(v1.z); o[7] = f2bf(v1.w);
    *(u16x8*)(xb + (size_t)i * 8) = o;
  }
}

// ---------------- K1: QKV GEMM (M=65536, N=1536, K=512) ----------------
// LDS layouts: As/Bs [kblk(8)][idx(128)][8] bf16, staged via global_load_lds x4.
__global__ __launch_bounds__(256) void k_qkv(const u16* __restrict__ xb,
                                             const u16* __restrict__ wl,
                                             u16* __restrict__ qkv) {
  __shared__ __align__(16) u16 As[8192];
  __shared__ __align__(16) u16 Bs[8192];
  const int tid = threadIdx.x, lane = tid & 63;
  const int wid = tid >> 6;
  // bijective XCD swizzle: 6144 wgs, 768 per XCD; cb fastest within chunk
  const int orig = blockIdx.x;
  const int wg = (orig & 7) * 768 + (orig >> 3);
  const int cb = wg % 12, rb = wg / 12;
  const int row0 = rb * 128, col0 = cb * 128;
  const int wr = wid >> 1, wc = wid & 1;
  f32x4 acc[4][4];
#pragma unroll
  for (int i = 0; i < 4; ++i)
#pragma unroll
    for (int j = 0; j < 4; ++j) acc[i][j] = (f32x4){0.f, 0.f, 0.f, 0.f};

  for (int kb = 0; kb < 8; ++kb) {
#pragma unroll
    for (int s4 = 0; s4 < 4; ++s4) {
      int slot = s4 * 256 + tid;
      int kblk = slot >> 7, m = slot & 127;
      gl_lds16(xb + (size_t)(row0 + m) * C_DIM + kb * 64 + kblk * 8, &As[slot * 8]);
    }
#pragma unroll
    for (int s4 = 0; s4 < 4; ++s4) {
      int slot = s4 * 256 + tid;
      int kblk = slot >> 7, n = slot & 127;
      gl_lds16(wl + ((size_t)(kb * 8 + kblk) * CQ3 + col0 + n) * 8, &Bs[slot * 8]);
    }
    __syncthreads();
#pragma unroll
    for (int kk = 0; kk < 2; ++kk) {
      const int krow = kk * 4 + (lane >> 4);
      bf16x8 af[4], bfr[4];
#pragma unroll
      for (int t = 0; t < 4; ++t)
        af[t] = *(const bf16x8*)&As[(krow * 128 + wr * 64 + t * 16 + (lane & 15)) * 8];
#pragma unroll
      for (int t = 0; t < 4; ++t)
        bfr[t] = *(const bf16x8*)&Bs[(krow * 128 + wc * 64 + t * 16 + (lane & 15)) * 8];
#pragma unroll
      for (int mt = 0; mt < 4; ++mt)
#pragma unroll
        for (int nt = 0; nt < 4; ++nt)
          acc[mt][nt] = __builtin_amdgcn_mfma_f32_16x16x32_bf16(af[mt], bfr[nt], acc[mt][nt], 0, 0, 0);
    }
    __syncthreads();
  }
  // epilogue: bf16 store. C/D layout: col = lane&15, row = (lane>>4)*4 + r
#pragma unroll
  for (int mt = 0; mt < 4; ++mt)
#pragma unroll
    for (int nt = 0; nt < 4; ++nt) {
      int col = col0 + wc * 64 + nt * 16 + (lane & 15);
#pragma unroll
      for (int r = 0; r < 4; ++r) {
        int row = row0 + wr * 64 + mt * 16 + (lane >> 4) * 4 + r;
        qkv[(size_t)row * CQ3 + col] = f2bf(acc[mt][nt][r]);
      }
    }
}

// ---------------- K2: Gram S[b,h] = Q^T K + sumsq (norms) ----------------
__global__ __launch_bounds__(256) void k_gram(const u16* __restrict__ qkv,
                                              float* __restrict__ Sp,
                                              float* __restrict__ ssq) {
  __shared__ __align__(16) u16 Qs[4][2048];   // [wave][nb2(4)][d(64)][8] bf16
  __shared__ __align__(16) u16 Ks[4][2048];
  __shared__ float Ssh[4096];
  __shared__ float ssqsh[128];
  const int tid = threadIdx.x, lane = tid & 63, wid = tid >> 6;
  const int nblk = blockIdx.x, bh = blockIdx.y;
  const int b = bh >> 3, hh = bh & 7;
  for (int i = tid; i < 4096; i += 256) Ssh[i] = 0.f;
  if (tid < 128) ssqsh[tid] = 0.f;
  __syncthreads();

  f32x4 acc[4][4];
#pragma unroll
  for (int i = 0; i < 4; ++i)
#pragma unroll
    for (int j = 0; j < 4; ++j) acc[i][j] = (f32x4){0.f, 0.f, 0.f, 0.f};
  float sq[8], sk[8];
#pragma unroll
  for (int i = 0; i < 8; ++i) { sq[i] = 0.f; sk[i] = 0.f; }

  const size_t rowbase = (size_t)b * N_TOK + (size_t)nblk * 1024 + wid * 256;
  const int colq = hh * 64;

  for (int it = 0; it < 8; ++it) {
#pragma unroll
    for (int j4 = 0; j4 < 4; ++j4) {
      int idx = j4 * 64 + lane;
      int n = idx >> 3;
      int dd0 = (idx & 7) * 8;
      const u16* gq = qkv + (rowbase + it * 32 + n) * CQ3 + colq + dd0;
      u16x8 q8 = *(const u16x8*)gq;
      u16x8 k8 = *(const u16x8*)(gq + C_DIM);
#pragma unroll
      for (int i = 0; i < 8; ++i) {
        float qf = bf2f(q8[i]); sq[i] += qf * qf;
        float kf = bf2f(k8[i]); sk[i] += kf * kf;
      }
      int base = ((n >> 3) * 64 + dd0) * 8 + (n & 7);   // transposed [nb2][d][nin]
#pragma unroll
      for (int i = 0; i < 8; ++i) {
        Qs[wid][base + i * 8] = q8[i];
        Ks[wid][base + i * 8] = k8[i];
      }
    }
    const int krow = lane >> 4;
    bf16x8 aq[4], ak[4];
#pragma unroll
    for (int m = 0; m < 4; ++m) {
      aq[m] = *(const bf16x8*)&Qs[wid][(krow * 64 + m * 16 + (lane & 15)) * 8];
      ak[m] = *(const bf16x8*)&Ks[wid][(krow * 64 + m * 16 + (lane & 15)) * 8];
    }
#pragma unroll
    for (int dm = 0; dm < 4; ++dm)
#pragma unroll
      for (int em = 0; em < 4; ++em)
        acc[dm][em] = __builtin_amdgcn_mfma_f32_16x16x32_bf16(aq[dm], ak[em], acc[dm][em], 0, 0, 0);
  }
#pragma unroll
  for (int dm = 0; dm < 4; ++dm)
#pragma unroll
    for (int em = 0; em < 4; ++em)
#pragma unroll
      for (int r = 0; r < 4; ++r)
        atomicAdd(&Ssh[(dm * 16 + (lane >> 4) * 4 + r) * 64 + em * 16 + (lane & 15)], acc[dm][em][r]);
#pragma unroll
  for (int i = 0; i < 8; ++i) {
    atomicAdd(&ssqsh[(lane & 7) * 8 + i], sq[i]);
    atomicAdd(&ssqsh[64 + (lane & 7) * 8 + i], sk[i]);
  }
  __syncthreads();
  float* sp = Sp + ((size_t)bh * 16 + nblk) * 4096;
  for (int i = tid; i < 4096; i += 256) sp[i] = Ssh[i];
  if (tid < 128) {
    int c = tid & 63;
    int off = (tid < 64) ? (colq + c) : (C_DIM + colq + c);
    atomicAdd(&ssq[b * 1024 + off], ssqsh[tid]);
  }
}

// ---------------- K3: softmax + fold into proj: M_b[c'=h*64+e][j] ----------------
__global__ __launch_bounds__(256) void k_attn_m(const float* __restrict__ Sp,
                                                const float* __restrict__ ssq,
                                                const float* __restrict__ temp,
                                                const float* __restrict__ pw,
                                                u16* __restrict__ Ml) {
  __shared__ float Ssh[4096];
  __shared__ float rq[64], rk[64];
  const int tid = threadIdx.x, lane = tid & 63, wid = tid >> 6;
  const int bh = blockIdx.x, b = bh >> 3, hh = bh & 7;
#pragma unroll
  for (int t2 = 0; t2 < 16; ++t2) {
    int idx = t2 * 256 + tid;
    float s = 0.f;
#pragma unroll
    for (int p = 0; p < 16; ++p) s += Sp[((size_t)bh * 16 + p) * 4096 + idx];
    Ssh[idx] = s;
  }
  if (tid < 64)
    rq[tid] = 1.f / fmaxf(sqrtf(ssq[b * 1024 + hh * 64 + tid]), 1e-12f);
  else if (tid < 128)
    rk[tid - 64] = 1.f / fmaxf(sqrtf(ssq[b * 1024 + C_DIM + hh * 64 + (tid - 64)]), 1e-12f);
  __syncthreads();
  const float tp = temp[hh];
  const int d = tid >> 2, q4 = tid & 3;
  float vals[16];
  float mx = -3.0e38f;
  const float rqd = rq[d];
#pragma unroll
  for (int i = 0; i < 16; ++i) {
    float v = Ssh[d * 64 + q4 * 16 + i] * rqd * rk[q4 * 16 + i] * tp;
    vals[i] = v; mx = fmaxf(mx, v);
  }
  mx = fmaxf(mx, __shfl_xor(mx, 1));
  mx = fmaxf(mx, __shfl_xor(mx, 2));
  float sum = 0.f;
#pragma unroll
  for (int i = 0; i < 16; ++i) { vals[i] = __expf(vals[i] - mx); sum += vals[i]; }
  sum += __shfl_xor(sum, 1);
  sum += __shfl_xor(sum, 2);
  const float inv = 1.f / sum;
#pragma unroll
  for (int i = 0; i < 16; ++i) Ssh[d * 64 + q4 * 16 + i] = vals[i] * inv;
  __syncthreads();
  f32x4 macc[4][8];
#pragma unroll
  for (int i = 0; i < 4; ++i)
#pragma unroll
    for (int j = 0; j < 8; ++j) macc[i][j] = (f32x4){0.f, 0.f, 0.f, 0.f};
#pragma unroll
  for (int kk = 0; kk < 2; ++kk) {
    bf16x8 af[4], bfr[8];
#pragma unroll
    for (int em = 0; em < 4; ++em) {
      u16x8 t8;
#pragma unroll
      for (int i = 0; i < 8; ++i) {
        int dd = kk * 32 + (lane >> 4) * 8 + i;
        t8[i] = f2bf(Ssh[dd * 64 + em * 16 + (lane & 15)]);
      }
      af[em] = as_bf16x8(t8);
    }
#pragma unroll
    for (int nt = 0; nt < 8; ++nt) {
      int j = wid * 128 + nt * 16 + (lane & 15);
      u16x8 t8;
#pragma unroll
      for (int i = 0; i < 8; ++i) {
        int dd = kk * 32 + (lane >> 4) * 8 + i;
        t8[i] = f2bf(pw[(size_t)(hh * 64 + dd) * C_DIM + j]);
      }
      bfr[nt] = as_bf16x8(t8);
    }
#pragma unroll
    for (int em = 0; em < 4; ++em)
#pragma unroll
      for (int nt = 0; nt < 8; ++nt)
        macc[em][nt] = __builtin_amdgcn_mfma_f32_16x16x32_bf16(af[em], bfr[nt], macc[em][nt], 0, 0, 0);
  }
#pragma unroll
  for (int em = 0; em < 4; ++em)
#pragma unroll
    for (int nt = 0; nt < 8; ++nt) {
      int j = wid * 128 + nt * 16 + (lane & 15);
#pragma unroll
      for (int r = 0; r < 4; ++r) {
        int e = em * 16 + (lane >> 4) * 4 + r;
        int cp = hh * 64 + e;
        Ml[(size_t)b * 262144 + ((size_t)(cp >> 3) * C_DIM + j) * 8 + (cp & 7)] = f2bf(macc[em][nt][r]);
      }
    }
}

// ---------------- K4: out = V @ M_b + bias (fp32 out) ----------------
__global__ __launch_bounds__(256) void k_out(const u16* __restrict__ qkv,
                                             const u16* __restrict__ Ml,
                                             const float* __restrict__ pb,
                                             float* __restrict__ out) {
  __shared__ __align__(16) u16 As[8192];
  __shared__ __align__(16) u16 Bs[8192];
  const int tid = threadIdx.x, lane = tid & 63, wid = tid >> 6;
  // bijective XCD swizzle: 2048 wgs, 256 per XCD; cb fastest
  const int orig = blockIdx.x;
  const int wg = (orig & 7) * 256 + (orig >> 3);
  const int b = wg >> 9;
  const int rem = wg & 511;
  const int rb = rem >> 2, cb = rem & 3;
  const int row0 = rb * 128, col0 = cb * 128;
  const int wr = wid >> 1, wc = wid & 1;
  f32x4 acc[4][4];
#pragma unroll
  for (int i = 0; i < 4; ++i)
#pragma unroll
    for (int j = 0; j < 4; ++j) acc[i][j] = (f32x4){0.f, 0.f, 0.f, 0.f};
  const u16* vbase = qkv + (size_t)b * N_TOK * CQ3 + 1024;   // V columns
  const u16* mbase = Ml + (size_t)b * 262144;

  for (int kb = 0; kb < 8; ++kb) {
#pragma unroll
    for (int s4 = 0; s4 < 4; ++s4) {
      int slot = s4 * 256 + tid;
      int kblk = slot >> 7, m = slot & 127;
      gl_lds16(vbase + (size_t)(row0 + m) * CQ3 + kb * 64 + kblk * 8, &As[slot * 8]);
    }
#pragma unroll
    for (int s4 = 0; s4 < 4; ++s4) {
      int slot = s4 * 256 + tid;
      int kblk = slot >> 7, n = slot & 127;
      gl_lds16(mbase + ((size_t)(kb * 8 + kblk) * C_DIM + col0 + n) * 8, &Bs[slot * 8]);
    }
    __syncthreads();
#pragma unroll
    for (int kk = 0; kk < 2; ++kk) {
      const int krow = kk * 4 + (lane >> 4);
      bf16x8 af[4], bfr[4];
#pragma unroll
      for (int t = 0; t < 4; ++t)
        af[t] = *(const bf16x8*)&As[(krow * 128 + wr * 64 + t * 16 + (lane & 15)) * 8];
#pragma unroll
      for (int t = 0; t < 4; ++t)
        bfr[t] = *(const bf16x8*)&Bs[(krow * 128 + wc * 64 + t * 16 + (lane & 15)) * 8];
#pragma unroll
      for (int mt = 0; mt < 4; ++mt)
#pragma unroll
        for (int nt = 0; nt < 4; ++nt)
          acc[mt][nt] = __builtin_amdgcn_mfma_f32_16x16x32_bf16(af[mt], bfr[nt], acc[mt][nt], 0, 0, 0);
    }
    __syncthreads();
  }
#pragma unroll
  for (int nt = 0; nt < 4; ++nt) {
    int col = col0 + wc * 64 + nt * 16 + (lane & 15);
    float bias = pb[col];
#pragma unroll
    for (int mt = 0; mt < 4; ++mt)
#pragma unroll
      for (int r = 0; r < 4; ++r) {
        int row = row0 + wr * 64 + mt * 16 + (lane >> 4) * 4 + r;
        out[((size_t)b * N_TOK + row) * C_DIM + col] = acc[mt][nt][r] + bias;
      }
  }
}

extern "C" void kernel_launch(void* const* d_in, const int* in_sizes, int n_in,
                              void* d_out, int out_size, void* d_ws, size_t ws_size,
                              hipStream_t stream) {
  const float* x      = (const float*)d_in[0];
  const float* qkv_w  = (const float*)d_in[3];
  const float* proj_w = (const float*)d_in[4];
  const float* proj_b = (const float*)d_in[5];
  const float* temp   = (const float*)d_in[6];
  float* out = (float*)d_out;

  char* ws = (char*)d_ws;
  const size_t XB_B  = (size_t)NROWS * C_DIM * 2;      // 67108864
  const size_t QKV_B = (size_t)NROWS * CQ3 * 2;        // 201326592
  const size_t WL_B  = (size_t)C_DIM * CQ3 * 2;        // 1572864
  const size_t SP_B  = (size_t)32 * 16 * 4096 * 4;     // 8388608
  const size_t SSQ_B = (size_t)4096 * 4;               // 16384
  u16*   xb  = (u16*)ws;
  u16*   qkv = (u16*)(ws + XB_B);
  u16*   wl  = (u16*)(ws + XB_B + QKV_B);
  float* Sp  = (float*)(ws + XB_B + QKV_B + WL_B);
  float* ssq = (float*)(ws + XB_B + QKV_B + WL_B + SP_B);
  u16*   Ml  = (u16*)(ws + XB_B + QKV_B + WL_B + SP_B + SSQ_B);

  k_zero<<<16, 256, 0, stream>>>(ssq, 4096);
  k_wswz<<<384, 256, 0, stream>>>(qkv_w, wl);
  k_xb<<<2048, 256, 0, stream>>>(x, xb);
  k_qkv<<<6144, 256, 0, stream>>>(xb, wl, qkv);
  k_gram<<<dim3(16, 32), 256, 0, stream>>>(qkv, Sp, ssq);
  k_attn_m<<<32, 256, 0, stream>>>(Sp, ssq, temp, proj_w, Ml);
  k_out<<<2048, 256, 0, stream>>>(qkv, Ml, proj_b, out);
}

// Round 3
// 358.279 us; speedup vs baseline: 1.3967x; 1.1054x over previous
//
#include <hip/hip_runtime.h>
#include <stdint.h>
#include <stddef.h>

// FastChannelAttention on MI355X.
//   K0a: zero ssq accumulators
//   K0b: swizzle qkv_w fp32 -> bf16 wl[(c/8)*1536 + j][8]
//   Kxb: x fp32 -> bf16 (row-major), once
//   K1 : qkv = xb @ wl   (256x256 8-phase pipelined bf16 MFMA, counted vmcnt)
//   K2 : S[b,h] = Q^T K (64x64 Gram over N) + sum-of-squares
//   K3 : attn = softmax(S/(|q||k|) * temp);  M_b = blockdiag(attn)^T @ proj_w
//   K4 : out = V @ M_b + proj_b  (same 256x256 8-phase pipeline, fp32 out)

typedef unsigned short u16;
typedef __attribute__((ext_vector_type(8))) unsigned short u16x8;
typedef __attribute__((ext_vector_type(8))) __bf16 bf16x8;
typedef __attribute__((ext_vector_type(4))) float f32x4;

#define B_DIM 4
#define N_TOK 16384
#define C_DIM 512
#define H_DIM 8
#define CQ3   1536
#define NROWS 65536

__device__ __forceinline__ u16 f2bf(float f) {              // RNE fp32->bf16
  union { float f; uint32_t u; } v; v.f = f;
  uint32_t r = v.u + 0x7FFFu + ((v.u >> 16) & 1u);
  return (u16)(r >> 16);
}
__device__ __forceinline__ float bf2f(u16 u) {
  union { uint32_t u; float f; } v; v.u = ((uint32_t)u) << 16;
  return v.f;
}
__device__ __forceinline__ bf16x8 as_bf16x8(u16x8 u) {
  union { u16x8 u; bf16x8 b; } v; v.u = u; return v.b;
}
__device__ __forceinline__ void gl_lds16(const void* g, void* l) {
  __builtin_amdgcn_global_load_lds(
      (const __attribute__((address_space(1))) uint32_t*)g,
      (__attribute__((address_space(3))) uint32_t*)l, 16, 0, 0);
}

#define VM4 asm volatile("s_waitcnt vmcnt(4)" ::: "memory")
#define VM0 asm volatile("s_waitcnt vmcnt(0)" ::: "memory")
#define NOVM ((void)0)

// One pipeline phase: [vmcnt?] barrier | ds_reads | stage issue | MFMA quadrant.
// Correctness: phase p's stage overwrites the half-tile last READ at p-2 (reads
// complete before p-2's MFMAs issue -> before p-1/p barriers); phase p's reads
// target halves staged >=5 phases ago, guaranteed by vmcnt(4)+barrier at p0/p4.
#define PH(BUF, KK, MH, VMOP, ...)                                             \
  {                                                                            \
    VMOP;                                                                      \
    __builtin_amdgcn_s_barrier();                                              \
    __builtin_amdgcn_sched_barrier(0);                                         \
    if ((MH) == 0) {                                                           \
      _Pragma("unroll") for (int nt = 0; nt < 4; ++nt)                         \
        bfr[nt] = *(const bf16x8*)&Bs[(BUF)*16384 + (KK)*8192 + nt*128 + bRd]; \
    }                                                                          \
    bf16x8 af[4];                                                              \
    _Pragma("unroll") for (int mt = 0; mt < 4; ++mt)                           \
      af[mt] = *(const bf16x8*)&As[(BUF)*16384 + (KK)*8192 + (MH)*512 + mt*128 + aRd]; \
    __VA_ARGS__;                                                               \
    __builtin_amdgcn_s_setprio(1);                                             \
    _Pragma("unroll") for (int mt = 0; mt < 4; ++mt)                           \
      _Pragma("unroll") for (int nt = 0; nt < 4; ++nt)                         \
        acc[(MH)*4 + mt][nt] = __builtin_amdgcn_mfma_f32_16x16x32_bf16(        \
            af[mt], bfr[nt], acc[(MH)*4 + mt][nt], 0, 0, 0);                   \
    __builtin_amdgcn_s_setprio(0);                                             \
    __builtin_amdgcn_sched_barrier(0);                                         \
  }

// 256x256 tile, BK=64, 8 waves (2Mx4N), K=512 (8 K-tiles), double-buffered LDS.
// LDS per K-tile buffer: [kblk(8)][idx(256)][8] bf16 slots of 16B (linear for
// global_load_lds, conflict-free for ds_read_b128).
template <int BT, int BH, int BJ>
__device__ __forceinline__ void gemm256_pipe(const u16* __restrict__ aSrc,
                                             const u16* __restrict__ bSrc,
                                             int tid, f32x4 (&acc)[8][4]) {
  __shared__ __align__(16) u16 As[32768];
  __shared__ __align__(16) u16 Bs[32768];
  const int lane = tid & 63, wid = tid >> 6;
  const int wr = wid >> 2, wc = wid & 3;
  const int aRd = ((lane >> 4) * 256 + wr * 128 + (lane & 15)) * 8;
  const int bRd = ((lane >> 4) * 256 + wc * 64 + (lane & 15)) * 8;
  u16* aD = &As[tid * 8];
  u16* bD = &Bs[tid * 8];

  auto stageA = [&](int t, int h) {
    const u16* s = aSrc + t * 64 + h * 32;
    u16* d = aD + (t & 1) * 16384 + h * 8192;
    gl_lds16(s, d);
    gl_lds16(s + 16, d + 4096);
  };
  auto stageB = [&](int t, int h) {
    const u16* s = bSrc + (size_t)t * BT + h * BH;
    u16* d = bD + (t & 1) * 16384 + h * 8192;
    gl_lds16(s, d);
    gl_lds16(s + BJ, d + 4096);
  };

  bf16x8 bfr[4];
  // prologue: tile0 all 4 halves + tile1 first 2 halves (12 loads/thread... 2 each)
  stageA(0, 0); stageB(0, 0); stageA(0, 1); stageB(0, 1); stageA(1, 0); stageB(1, 0);

  for (int i = 0; i < 3; ++i) {
    const int a = 2 * i, b = 2 * i + 1;
    PH(0, 0, 0, VM4,  stageA(b, 1));
    PH(0, 0, 1, NOVM, stageB(b, 1));
    PH(0, 1, 0, NOVM, stageA(a + 2, 0));
    PH(0, 1, 1, NOVM, stageB(a + 2, 0));
    PH(1, 0, 0, VM4,  stageA(a + 2, 1));
    PH(1, 0, 1, NOVM, stageB(a + 2, 1));
    PH(1, 1, 0, NOVM, stageA(b + 2, 0));
    PH(1, 1, 1, NOVM, stageB(b + 2, 0));
  }
  // epilogue: tiles 6,7
  PH(0, 0, 0, VM4,  stageA(7, 1));
  PH(0, 0, 1, NOVM, stageB(7, 1));
  PH(0, 1, 0, NOVM, );
  PH(0, 1, 1, NOVM, );
  PH(1, 0, 0, VM0,  );
  PH(1, 0, 1, NOVM, );
  PH(1, 1, 0, NOVM, );
  PH(1, 1, 1, NOVM, );
}

// ---------------- K0a: zero ----------------
__global__ void k_zero(float* p, int n) {
  int i = blockIdx.x * 256 + threadIdx.x;
  if (i < n) p[i] = 0.f;
}

// ---------------- K0b: weight swizzle fp32 -> bf16 [(c/8)*1536 + j][8] ----------------
__global__ __launch_bounds__(256) void k_wswz(const float* __restrict__ w, u16* __restrict__ wl) {
  int g = blockIdx.x * 256 + threadIdx.x;       // 0..98303 slots
  int c8 = g / CQ3, j = g - c8 * CQ3;
  u16x8 o;
#pragma unroll
  for (int i = 0; i < 8; ++i) o[i] = f2bf(w[(size_t)(c8 * 8 + i) * CQ3 + j]);
  *(u16x8*)(wl + (size_t)g * 8) = o;
}

// ---------------- Kxb: x fp32 -> bf16 row-major ----------------
__global__ __launch_bounds__(256) void k_xb(const float* __restrict__ x, u16* __restrict__ xb) {
  const int nchunk = NROWS * C_DIM / 8;          // 4194304
  const int stride = 2048 * 256;
  for (int i = blockIdx.x * 256 + threadIdx.x; i < nchunk; i += stride) {
    float4 v0 = *(const float4*)(x + (size_t)i * 8);
    float4 v1 = *(const float4*)(x + (size_t)i * 8 + 4);
    u16x8 o;
    o[0] = f2bf(v0.x); o[1] = f2bf(v0.y); o[2] = f2bf(v0.z); o[3] = f2bf(v0.w);
    o[4] = f2bf(v1.x); o[5] = f2bf(v1.y); o[6] = f2bf(v1.z); o[7] = f2bf(v1.w);
    *(u16x8*)(xb + (size_t)i * 8) = o;
  }
}

// ---------------- K1: QKV GEMM (M=65536, N=1536, K=512), 256^2 8-phase ----------------
__global__ __launch_bounds__(512) void k_qkv(const u16* __restrict__ xb,
                                             const u16* __restrict__ wl,
                                             u16* __restrict__ qkv) {
  const int tid = threadIdx.x;
  // bijective XCD swizzle: 1536 wgs = 8 x 192; cb fastest within chunk
  const int orig = blockIdx.x;
  const int wg = (orig & 7) * 192 + (orig >> 3);
  const int cb = wg % 6, rb = wg / 6;
  const int row0 = rb * 256, col0 = cb * 256;
  const u16* aSrc = xb + (size_t)(row0 + (tid & 255)) * C_DIM + (tid >> 8) * 8;
  const u16* bSrc = wl + (tid >> 8) * 12288 + (size_t)(col0 + (tid & 255)) * 8;

  f32x4 acc[8][4];
#pragma unroll
  for (int i = 0; i < 8; ++i)
#pragma unroll
    for (int j = 0; j < 4; ++j) acc[i][j] = (f32x4){0.f, 0.f, 0.f, 0.f};

  gemm256_pipe<98304, 49152, 24576>(aSrc, bSrc, tid, acc);

  const int lane = tid & 63, wid = tid >> 6, wr = wid >> 2, wc = wid & 3;
#pragma unroll
  for (int mt = 0; mt < 8; ++mt)
#pragma unroll
    for (int nt = 0; nt < 4; ++nt) {
      int col = col0 + wc * 64 + nt * 16 + (lane & 15);
#pragma unroll
      for (int r = 0; r < 4; ++r) {
        int row = row0 + wr * 128 + mt * 16 + (lane >> 4) * 4 + r;
        qkv[(size_t)row * CQ3 + col] = f2bf(acc[mt][nt][r]);
      }
    }
}

// ---------------- K4: out = V @ M_b + bias (fp32 out), 256^2 8-phase ----------------
__global__ __launch_bounds__(512) void k_out(const u16* __restrict__ qkv,
                                             const u16* __restrict__ Ml,
                                             const float* __restrict__ pb,
                                             float* __restrict__ out) {
  const int tid = threadIdx.x;
  // bijective XCD swizzle: 512 wgs = 8 x 64; cb fastest
  const int orig = blockIdx.x;
  const int wg = (orig & 7) * 64 + (orig >> 3);
  const int cb = wg & 1, rb = wg >> 1;
  const int row0 = rb * 256, col0 = cb * 256;    // row0 spans batches (16384 rows each)
  const int b = rb >> 6;
  const u16* aSrc = qkv + (size_t)(row0 + (tid & 255)) * CQ3 + 1024 + (tid >> 8) * 8;
  const u16* bSrc = Ml + (size_t)b * 262144 + (tid >> 8) * 4096 + (size_t)(col0 + (tid & 255)) * 8;

  f32x4 acc[8][4];
#pragma unroll
  for (int i = 0; i < 8; ++i)
#pragma unroll
    for (int j = 0; j < 4; ++j) acc[i][j] = (f32x4){0.f, 0.f, 0.f, 0.f};

  gemm256_pipe<32768, 16384, 8192>(aSrc, bSrc, tid, acc);

  const int lane = tid & 63, wid = tid >> 6, wr = wid >> 2, wc = wid & 3;
#pragma unroll
  for (int nt = 0; nt < 4; ++nt) {
    int col = col0 + wc * 64 + nt * 16 + (lane & 15);
    float bias = pb[col];
#pragma unroll
    for (int mt = 0; mt < 8; ++mt)
#pragma unroll
      for (int r = 0; r < 4; ++r) {
        int row = row0 + wr * 128 + mt * 16 + (lane >> 4) * 4 + r;
        out[(size_t)row * C_DIM + col] = acc[mt][nt][r] + bias;
      }
  }
}

// ---------------- K2: Gram S[b,h] = Q^T K + sumsq (norms) ----------------
__global__ __launch_bounds__(256) void k_gram(const u16* __restrict__ qkv,
                                              float* __restrict__ Sp,
                                              float* __restrict__ ssq) {
  __shared__ __align__(16) u16 Qs[4][2048];   // [wave][nb2(4)][d(64)][8] bf16
  __shared__ __align__(16) u16 Ks[4][2048];
  __shared__ float Ssh[4096];
  __shared__ float ssqsh[128];
  const int tid = threadIdx.x, lane = tid & 63, wid = tid >> 6;
  const int nblk = blockIdx.x, bh = blockIdx.y;
  const int b = bh >> 3, hh = bh & 7;
  for (int i = tid; i < 4096; i += 256) Ssh[i] = 0.f;
  if (tid < 128) ssqsh[tid] = 0.f;
  __syncthreads();

  f32x4 acc[4][4];
#pragma unroll
  for (int i = 0; i < 4; ++i)
#pragma unroll
    for (int j = 0; j < 4; ++j) acc[i][j] = (f32x4){0.f, 0.f, 0.f, 0.f};
  float sq[8], sk[8];
#pragma unroll
  for (int i = 0; i < 8; ++i) { sq[i] = 0.f; sk[i] = 0.f; }

  const size_t rowbase = (size_t)b * N_TOK + (size_t)nblk * 1024 + wid * 256;
  const int colq = hh * 64;

  for (int it = 0; it < 8; ++it) {
#pragma unroll
    for (int j4 = 0; j4 < 4; ++j4) {
      int idx = j4 * 64 + lane;
      int n = idx >> 3;
      int dd0 = (idx & 7) * 8;
      const u16* gq = qkv + (rowbase + it * 32 + n) * CQ3 + colq + dd0;
      u16x8 q8 = *(const u16x8*)gq;
      u16x8 k8 = *(const u16x8*)(gq + C_DIM);
#pragma unroll
      for (int i = 0; i < 8; ++i) {
        float qf = bf2f(q8[i]); sq[i] += qf * qf;
        float kf = bf2f(k8[i]); sk[i] += kf * kf;
      }
      int base = ((n >> 3) * 64 + dd0) * 8 + (n & 7);   // transposed [nb2][d][nin]
#pragma unroll
      for (int i = 0; i < 8; ++i) {
        Qs[wid][base + i * 8] = q8[i];
        Ks[wid][base + i * 8] = k8[i];
      }
    }
    const int krow = lane >> 4;
    bf16x8 aq[4], ak[4];
#pragma unroll
    for (int m = 0; m < 4; ++m) {
      aq[m] = *(const bf16x8*)&Qs[wid][(krow * 64 + m * 16 + (lane & 15)) * 8];
      ak[m] = *(const bf16x8*)&Ks[wid][(krow * 64 + m * 16 + (lane & 15)) * 8];
    }
#pragma unroll
    for (int dm = 0; dm < 4; ++dm)
#pragma unroll
      for (int em = 0; em < 4; ++em)
        acc[dm][em] = __builtin_amdgcn_mfma_f32_16x16x32_bf16(aq[dm], ak[em], acc[dm][em], 0, 0, 0);
  }
#pragma unroll
  for (int dm = 0; dm < 4; ++dm)
#pragma unroll
    for (int em = 0; em < 4; ++em)
#pragma unroll
      for (int r = 0; r < 4; ++r)
        atomicAdd(&Ssh[(dm * 16 + (lane >> 4) * 4 + r) * 64 + em * 16 + (lane & 15)], acc[dm][em][r]);
#pragma unroll
  for (int i = 0; i < 8; ++i) {
    atomicAdd(&ssqsh[(lane & 7) * 8 + i], sq[i]);
    atomicAdd(&ssqsh[64 + (lane & 7) * 8 + i], sk[i]);
  }
  __syncthreads();
  float* sp = Sp + ((size_t)bh * 16 + nblk) * 4096;
  for (int i = tid; i < 4096; i += 256) sp[i] = Ssh[i];
  if (tid < 128) {
    int c = tid & 63;
    int off = (tid < 64) ? (colq + c) : (C_DIM + colq + c);
    atomicAdd(&ssq[b * 1024 + off], ssqsh[tid]);
  }
}

// ---------------- K3: softmax + fold into proj: M_b[c'=h*64+e][j] ----------------
__global__ __launch_bounds__(256) void k_attn_m(const float* __restrict__ Sp,
                                                const float* __restrict__ ssq,
                                                const float* __restrict__ temp,
                                                const float* __restrict__ pw,
                                                u16* __restrict__ Ml) {
  __shared__ float Ssh[4096];
  __shared__ float rq[64], rk[64];
  const int tid = threadIdx.x, lane = tid & 63, wid = tid >> 6;
  const int bh = blockIdx.x, b = bh >> 3, hh = bh & 7;
#pragma unroll
  for (int t2 = 0; t2 < 16; ++t2) {
    int idx = t2 * 256 + tid;
    float s = 0.f;
#pragma unroll
    for (int p = 0; p < 16; ++p) s += Sp[((size_t)bh * 16 + p) * 4096 + idx];
    Ssh[idx] = s;
  }
  if (tid < 64)
    rq[tid] = 1.f / fmaxf(sqrtf(ssq[b * 1024 + hh * 64 + tid]), 1e-12f);
  else if (tid < 128)
    rk[tid - 64] = 1.f / fmaxf(sqrtf(ssq[b * 1024 + C_DIM + hh * 64 + (tid - 64)]), 1e-12f);
  __syncthreads();
  const float tp = temp[hh];
  const int d = tid >> 2, q4 = tid & 3;
  float vals[16];
  float mx = -3.0e38f;
  const float rqd = rq[d];
#pragma unroll
  for (int i = 0; i < 16; ++i) {
    float v = Ssh[d * 64 + q4 * 16 + i] * rqd * rk[q4 * 16 + i] * tp;
    vals[i] = v; mx = fmaxf(mx, v);
  }
  mx = fmaxf(mx, __shfl_xor(mx, 1));
  mx = fmaxf(mx, __shfl_xor(mx, 2));
  float sum = 0.f;
#pragma unroll
  for (int i = 0; i < 16; ++i) { vals[i] = __expf(vals[i] - mx); sum += vals[i]; }
  sum += __shfl_xor(sum, 1);
  sum += __shfl_xor(sum, 2);
  const float inv = 1.f / sum;
#pragma unroll
  for (int i = 0; i < 16; ++i) Ssh[d * 64 + q4 * 16 + i] = vals[i] * inv;
  __syncthreads();
  f32x4 macc[4][8];
#pragma unroll
  for (int i = 0; i < 4; ++i)
#pragma unroll
    for (int j = 0; j < 8; ++j) macc[i][j] = (f32x4){0.f, 0.f, 0.f, 0.f};
#pragma unroll
  for (int kk = 0; kk < 2; ++kk) {
    bf16x8 af[4], bfr[8];
#pragma unroll
    for (int em = 0; em < 4; ++em) {
      u16x8 t8;
#pragma unroll
      for (int i = 0; i < 8; ++i) {
        int dd = kk * 32 + (lane >> 4) * 8 + i;
        t8[i] = f2bf(Ssh[dd * 64 + em * 16 + (lane & 15)]);
      }
      af[em] = as_bf16x8(t8);
    }
#pragma unroll
    for (int nt = 0; nt < 8; ++nt) {
      int j = wid * 128 + nt * 16 + (lane & 15);
      u16x8 t8;
#pragma unroll
      for (int i = 0; i < 8; ++i) {
        int dd = kk * 32 + (lane >> 4) * 8 + i;
        t8[i] = f2bf(pw[(size_t)(hh * 64 + dd) * C_DIM + j]);
      }
      bfr[nt] = as_bf16x8(t8);
    }
#pragma unroll
    for (int em = 0; em < 4; ++em)
#pragma unroll
      for (int nt = 0; nt < 8; ++nt)
        macc[em][nt] = __builtin_amdgcn_mfma_f32_16x16x32_bf16(af[em], bfr[nt], macc[em][nt], 0, 0, 0);
  }
#pragma unroll
  for (int em = 0; em < 4; ++em)
#pragma unroll
    for (int nt = 0; nt < 8; ++nt) {
      int j = wid * 128 + nt * 16 + (lane & 15);
#pragma unroll
      for (int r = 0; r < 4; ++r) {
        int e = em * 16 + (lane >> 4) * 4 + r;
        int cp = hh * 64 + e;
        Ml[(size_t)b * 262144 + ((size_t)(cp >> 3) * C_DIM + j) * 8 + (cp & 7)] = f2bf(macc[em][nt][r]);
      }
    }
}

extern "C" void kernel_launch(void* const* d_in, const int* in_sizes, int n_in,
                              void* d_out, int out_size, void* d_ws, size_t ws_size,
                              hipStream_t stream) {
  const float* x      = (const float*)d_in[0];
  const float* qkv_w  = (const float*)d_in[3];
  const float* proj_w = (const float*)d_in[4];
  const float* proj_b = (const float*)d_in[5];
  const float* temp   = (const float*)d_in[6];
  float* out = (float*)d_out;

  char* ws = (char*)d_ws;
  const size_t XB_B  = (size_t)NROWS * C_DIM * 2;      // 67108864
  const size_t QKV_B = (size_t)NROWS * CQ3 * 2;        // 201326592
  const size_t WL_B  = (size_t)C_DIM * CQ3 * 2;        // 1572864
  const size_t SP_B  = (size_t)32 * 16 * 4096 * 4;     // 8388608
  const size_t SSQ_B = (size_t)4096 * 4;               // 16384
  u16*   xb  = (u16*)ws;
  u16*   qkv = (u16*)(ws + XB_B);
  u16*   wl  = (u16*)(ws + XB_B + QKV_B);
  float* Sp  = (float*)(ws + XB_B + QKV_B + WL_B);
  float* ssq = (float*)(ws + XB_B + QKV_B + WL_B + SP_B);
  u16*   Ml  = (u16*)(ws + XB_B + QKV_B + WL_B + SP_B + SSQ_B);

  k_zero<<<16, 256, 0, stream>>>(ssq, 4096);
  k_wswz<<<384, 256, 0, stream>>>(qkv_w, wl);
  k_xb<<<2048, 256, 0, stream>>>(x, xb);
  k_qkv<<<1536, 512, 0, stream>>>(xb, wl, qkv);
  k_gram<<<dim3(16, 32), 256, 0, stream>>>(qkv, Sp, ssq);
  k_attn_m<<<32, 256, 0, stream>>>(Sp, ssq, temp, proj_w, Ml);
  k_out<<<512, 512, 0, stream>>>(qkv, Ml, proj_b, out);
}

// Round 4
// 355.720 us; speedup vs baseline: 1.4068x; 1.0072x over previous
//
#include <hip/hip_runtime.h>
#include <stdint.h>
#include <stddef.h>

// FastChannelAttention on MI355X.
//   K0a: zero ssq accumulators
//   K0b: swizzle qkv_w fp32 -> bf16 wl[(c/8)*1536 + j][8]
//   Kxb: x fp32 -> bf16 (row-major), once
//   K1 : qkv = xb @ wl   (256x256 8-phase pipelined bf16 MFMA, counted vmcnt,
//        reads-before-barrier order per m201 template, LDS-staged epilogue)
//   K2 : S[b,h] = Q^T K (64x64 Gram over N) + sum-of-squares
//   K3 : attn = softmax(S/(|q||k|) * temp);  M_b = blockdiag(attn)^T @ proj_w
//   K4 : out = V @ M_b + proj_b  (same pipeline, fp32 out)

typedef unsigned short u16;
typedef __attribute__((ext_vector_type(8))) unsigned short u16x8;
typedef __attribute__((ext_vector_type(8))) __bf16 bf16x8;
typedef __attribute__((ext_vector_type(4))) float f32x4;

#define B_DIM 4
#define N_TOK 16384
#define C_DIM 512
#define H_DIM 8
#define CQ3   1536
#define NROWS 65536

__device__ __forceinline__ u16 f2bf(float f) {              // RNE fp32->bf16
  union { float f; uint32_t u; } v; v.f = f;
  uint32_t r = v.u + 0x7FFFu + ((v.u >> 16) & 1u);
  return (u16)(r >> 16);
}
__device__ __forceinline__ float bf2f(u16 u) {
  union { uint32_t u; float f; } v; v.u = ((uint32_t)u) << 16;
  return v.f;
}
__device__ __forceinline__ bf16x8 as_bf16x8(u16x8 u) {
  union { u16x8 u; bf16x8 b; } v; v.u = u; return v.b;
}
__device__ __forceinline__ void gl_lds16(const void* g, void* l) {
  __builtin_amdgcn_global_load_lds(
      (const __attribute__((address_space(1))) uint32_t*)g,
      (__attribute__((address_space(3))) uint32_t*)l, 16, 0, 0);
}

#define VM8 asm volatile("s_waitcnt vmcnt(8)" ::: "memory")
#define VM4 asm volatile("s_waitcnt vmcnt(4)" ::: "memory")
#define VM0 asm volatile("s_waitcnt vmcnt(0)" ::: "memory")
#define NOVM ((void)0)

// Phase (m201 order): {ds_read | stage issue | vmcnt?} -> barrier -> MFMA -> barrier.
// Reads issue BEFORE barrier1 so LDS latency overlaps the barrier wait.
// Hazard proof: reads_p complete before MFMA_p (compiler lgkmcnt) < barrier2_p;
// any stage_q overwriting that region has q >= p+2, issued after barrier2_{q-1}
// >= barrier2_{p+1} > barrier2_p.  Landing guarantee: VMOP at phase p-1 (before
// barrier1_{p-1}) + that barrier makes (all but newest N loads landed) collective
// before reads_p, which occur after barrier2_{p-1}.
#define PH(BUF, KK, MH, VMOP, ...)                                             \
  {                                                                            \
    if ((MH) == 0) {                                                           \
      _Pragma("unroll") for (int nt = 0; nt < 4; ++nt)                         \
        bfr[nt] = *(const bf16x8*)&Bs[(BUF)*16384 + (KK)*8192 + nt*128 + bRd]; \
    }                                                                          \
    bf16x8 af[4];                                                              \
    _Pragma("unroll") for (int mt = 0; mt < 4; ++mt)                           \
      af[mt] = *(const bf16x8*)&As[(BUF)*16384 + (KK)*8192 + (MH)*512 + mt*128 + aRd]; \
    __VA_ARGS__;                                                               \
    VMOP;                                                                      \
    __builtin_amdgcn_sched_barrier(0);                                         \
    __builtin_amdgcn_s_barrier();                                              \
    __builtin_amdgcn_s_setprio(1);                                             \
    _Pragma("unroll") for (int mt = 0; mt < 4; ++mt)                           \
      _Pragma("unroll") for (int nt = 0; nt < 4; ++nt)                         \
        acc[(MH)*4 + mt][nt] = __builtin_amdgcn_mfma_f32_16x16x32_bf16(        \
            af[mt], bfr[nt], acc[(MH)*4 + mt][nt], 0, 0, 0);                   \
    __builtin_amdgcn_s_setprio(0);                                             \
    __builtin_amdgcn_sched_barrier(0);                                         \
    __builtin_amdgcn_s_barrier();                                              \
    __builtin_amdgcn_sched_barrier(0);                                         \
  }

// 256x256 tile, BK=64, 8 waves (2Mx4N), K=512 (8 K-tiles), double-buffered LDS.
// Buffers: [kblk(8)][idx(256)][8] bf16 16B slots (linear for global_load_lds,
// conflict-free ds_read_b128).
template <int BT, int BH, int BJ>
__device__ __forceinline__ void gemm256_pipe(const u16* __restrict__ aSrc,
                                             const u16* __restrict__ bSrc,
                                             int tid, f32x4 (&acc)[8][4],
                                             u16 (&As)[32768], u16 (&Bs)[32768]) {
  const int lane = tid & 63, wid = tid >> 6;
  const int wr = wid >> 2, wc = wid & 3;
  const int aRd = ((lane >> 4) * 256 + wr * 128 + (lane & 15)) * 8;
  const int bRd = ((lane >> 4) * 256 + wc * 64 + (lane & 15)) * 8;
  u16* aD = &As[tid * 8];
  u16* bD = &Bs[tid * 8];

  auto stageA = [&](int t, int h) {
    const u16* s = aSrc + t * 64 + h * 32;
    u16* d = aD + (t & 1) * 16384 + h * 8192;
    gl_lds16(s, d);
    gl_lds16(s + 16, d + 4096);
  };
  auto stageB = [&](int t, int h) {
    const u16* s = bSrc + (size_t)t * BT + h * BH;
    u16* d = bD + (t & 1) * 16384 + h * 8192;
    gl_lds16(s, d);
    gl_lds16(s + BJ, d + 4096);
  };

  bf16x8 bfr[4];
  // prologue: tile0 (4 halves) + tile1 h0  = 12 loads/thread
  stageA(0, 0); stageB(0, 0); stageA(0, 1); stageB(0, 1); stageA(1, 0); stageB(1, 0);
  VM8;                                  // oldest 4 (A00,B00) landed
  __builtin_amdgcn_sched_barrier(0);
  __builtin_amdgcn_s_barrier();

  for (int i = 0; i < 3; ++i) {
    const int a = 2 * i, b = 2 * i + 1;
    PH(0, 0, 0, NOVM, stageA(b, 1));
    PH(0, 0, 1, VM8,  stageB(b, 1));
    PH(0, 1, 0, NOVM, stageA(a + 2, 0));
    PH(0, 1, 1, VM8,  stageB(a + 2, 0));
    PH(1, 0, 0, NOVM, stageA(a + 2, 1));
    PH(1, 0, 1, VM8,  stageB(a + 2, 1));
    PH(1, 1, 0, NOVM, stageA(b + 2, 0));
    PH(1, 1, 1, VM8,  stageB(b + 2, 0));
  }
  // epilogue: tiles 6,7
  PH(0, 0, 0, NOVM, stageA(7, 1));
  PH(0, 0, 1, VM8,  stageB(7, 1));
  PH(0, 1, 0, NOVM, );
  PH(0, 1, 1, VM4,  );
  PH(1, 0, 0, NOVM, );
  PH(1, 0, 1, VM0,  );
  PH(1, 1, 0, NOVM, );
  PH(1, 1, 1, NOVM, );
}

// ---------------- K0a: zero ----------------
__global__ void k_zero(float* p, int n) {
  int i = blockIdx.x * 256 + threadIdx.x;
  if (i < n) p[i] = 0.f;
}

// ---------------- K0b: weight swizzle fp32 -> bf16 [(c/8)*1536 + j][8] ----------------
__global__ __launch_bounds__(256) void k_wswz(const float* __restrict__ w, u16* __restrict__ wl) {
  int g = blockIdx.x * 256 + threadIdx.x;       // 0..98303 slots
  int c8 = g / CQ3, j = g - c8 * CQ3;
  u16x8 o;
#pragma unroll
  for (int i = 0; i < 8; ++i) o[i] = f2bf(w[(size_t)(c8 * 8 + i) * CQ3 + j]);
  *(u16x8*)(wl + (size_t)g * 8) = o;
}

// ---------------- Kxb: x fp32 -> bf16 row-major ----------------
__global__ __launch_bounds__(256) void k_xb(const float* __restrict__ x, u16* __restrict__ xb) {
  const int nchunk = NROWS * C_DIM / 8;          // 4194304
  const int stride = 2048 * 256;
  for (int i = blockIdx.x * 256 + threadIdx.x; i < nchunk; i += stride) {
    float4 v0 = *(const float4*)(x + (size_t)i * 8);
    float4 v1 = *(const float4*)(x + (size_t)i * 8 + 4);
    u16x8 o;
    o[0] = f2bf(v0.x); o[1] = f2bf(v0.y); o[2] = f2bf(v0.z); o[3] = f2bf(v0.w);
    o[4] = f2bf(v1.x); o[5] = f2bf(v1.y); o[6] = f2bf(v1.z); o[7] = f2bf(v1.w);
    *(u16x8*)(xb + (size_t)i * 8) = o;
  }
}

// ---------------- K1: QKV GEMM (M=65536, N=1536, K=512), 256^2 8-phase ----------------
__global__ __launch_bounds__(512) void k_qkv(const u16* __restrict__ xb,
                                             const u16* __restrict__ wl,
                                             u16* __restrict__ qkv) {
  __shared__ __align__(16) u16 As[32768];
  __shared__ __align__(16) u16 Bs[32768];
  const int tid = threadIdx.x;
  // bijective XCD swizzle: 1536 wgs = 8 x 192; cb fastest within chunk
  const int orig = blockIdx.x;
  const int wg = (orig & 7) * 192 + (orig >> 3);
  const int cb = wg % 6, rb = wg / 6;
  const int row0 = rb * 256, col0 = cb * 256;
  const u16* aSrc = xb + (size_t)(row0 + (tid & 255)) * C_DIM + (tid >> 8) * 8;
  const u16* bSrc = wl + (tid >> 8) * 12288 + (size_t)(col0 + (tid & 255)) * 8;

  f32x4 acc[8][4];
#pragma unroll
  for (int i = 0; i < 8; ++i)
#pragma unroll
    for (int j = 0; j < 4; ++j) acc[i][j] = (f32x4){0.f, 0.f, 0.f, 0.f};

  gemm256_pipe<98304, 49152, 24576>(aSrc, bSrc, tid, acc, As, Bs);

  // epilogue: wave-private LDS staging (16KB/wave), XOR-swizzled, b128 out
  const int lane = tid & 63, wid = tid >> 6, wr = wid >> 2, wc = wid & 3;
  u16* w = (wid < 4) ? &As[wid * 8192] : &Bs[(wid - 4) * 8192];
#pragma unroll
  for (int mt = 0; mt < 8; ++mt)
#pragma unroll
    for (int nt = 0; nt < 4; ++nt)
#pragma unroll
      for (int r = 0; r < 4; ++r) {
        int row = mt * 16 + (lane >> 4) * 4 + r;
        int col = nt * 16 + (lane & 15);
        int slot = (col >> 3) ^ (row & 7);
        w[row * 64 + slot * 8 + (col & 7)] = f2bf(acc[mt][nt][r]);
      }
  // wave-private: no barrier needed (in-wave LDS ordering via lgkmcnt)
#pragma unroll
  for (int it = 0; it < 16; ++it) {
    int rr = it * 8 + (lane >> 3);
    int slot = (lane & 7) ^ (rr & 7);
    *(u16x8*)&qkv[(size_t)(row0 + wr * 128 + rr) * CQ3 + col0 + wc * 64 + (lane & 7) * 8] =
        *(const u16x8*)&w[rr * 64 + slot * 8];
  }
}

// ---------------- K4: out = V @ M_b + bias (fp32 out), 256^2 8-phase ----------------
__global__ __launch_bounds__(512) void k_out(const u16* __restrict__ qkv,
                                             const u16* __restrict__ Ml,
                                             const float* __restrict__ pb,
                                             float* __restrict__ out) {
  __shared__ __align__(16) u16 As[32768];
  __shared__ __align__(16) u16 Bs[32768];
  const int tid = threadIdx.x;
  // bijective XCD swizzle: 512 wgs = 8 x 64; cb fastest
  const int orig = blockIdx.x;
  const int wg = (orig & 7) * 64 + (orig >> 3);
  const int cb = wg & 1, rb = wg >> 1;
  const int row0 = rb * 256, col0 = cb * 256;    // row0 spans batches (16384 rows each)
  const int b = rb >> 6;
  const u16* aSrc = qkv + (size_t)(row0 + (tid & 255)) * CQ3 + 1024 + (tid >> 8) * 8;
  const u16* bSrc = Ml + (size_t)b * 262144 + (tid >> 8) * 4096 + (size_t)(col0 + (tid & 255)) * 8;

  const int lane = tid & 63, wid = tid >> 6, wr = wid >> 2, wc = wid & 3;
  float bias[4];
#pragma unroll
  for (int nt = 0; nt < 4; ++nt) bias[nt] = pb[col0 + wc * 64 + nt * 16 + (lane & 15)];

  f32x4 acc[8][4];
#pragma unroll
  for (int i = 0; i < 8; ++i)
#pragma unroll
    for (int j = 0; j < 4; ++j) acc[i][j] = (f32x4){0.f, 0.f, 0.f, 0.f};

  gemm256_pipe<32768, 16384, 8192>(aSrc, bSrc, tid, acc, As, Bs);

  // epilogue: fp32, two 64-row halves through wave-private 16KB LDS slice
  float* w = (float*)((wid < 4) ? (void*)&As[wid * 8192] : (void*)&Bs[(wid - 4) * 8192]);
#pragma unroll
  for (int half = 0; half < 2; ++half) {
#pragma unroll
    for (int mt = 0; mt < 4; ++mt)
#pragma unroll
      for (int nt = 0; nt < 4; ++nt)
#pragma unroll
        for (int r = 0; r < 4; ++r) {
          int row = mt * 16 + (lane >> 4) * 4 + r;            // 0..63
          int col = nt * 16 + (lane & 15);
          int slot = (col >> 2) ^ (row & 15);
          w[row * 64 + slot * 4 + (col & 3)] = acc[half * 4 + mt][nt][r] + bias[nt];
        }
#pragma unroll
    for (int it = 0; it < 16; ++it) {
      int rr = it * 4 + (lane >> 4);                          // 0..63
      int s = (lane & 15) ^ (rr & 15);
      *(float4*)&out[(size_t)(row0 + wr * 128 + half * 64 + rr) * C_DIM + col0 + wc * 64 + (lane & 15) * 4] =
          *(const float4*)&w[rr * 64 + s * 4];
    }
  }
}

// ---------------- K2: Gram S[b,h] = Q^T K + sumsq (norms) ----------------
__global__ __launch_bounds__(256) void k_gram(const u16* __restrict__ qkv,
                                              float* __restrict__ Sp,
                                              float* __restrict__ ssq) {
  __shared__ __align__(16) u16 Qs[4][2048];   // [wave][nb2(4)][d(64)][8] bf16
  __shared__ __align__(16) u16 Ks[4][2048];
  __shared__ float Ssh[4096];
  __shared__ float ssqsh[128];
  const int tid = threadIdx.x, lane = tid & 63, wid = tid >> 6;
  const int nblk = blockIdx.x, bh = blockIdx.y;
  const int b = bh >> 3, hh = bh & 7;
  for (int i = tid; i < 4096; i += 256) Ssh[i] = 0.f;
  if (tid < 128) ssqsh[tid] = 0.f;
  __syncthreads();

  f32x4 acc[4][4];
#pragma unroll
  for (int i = 0; i < 4; ++i)
#pragma unroll
    for (int j = 0; j < 4; ++j) acc[i][j] = (f32x4){0.f, 0.f, 0.f, 0.f};
  float sq[8], sk[8];
#pragma unroll
  for (int i = 0; i < 8; ++i) { sq[i] = 0.f; sk[i] = 0.f; }

  const size_t rowbase = (size_t)b * N_TOK + (size_t)nblk * 1024 + wid * 256;
  const int colq = hh * 64;

  for (int it = 0; it < 8; ++it) {
#pragma unroll
    for (int j4 = 0; j4 < 4; ++j4) {
      int idx = j4 * 64 + lane;
      int n = idx >> 3;
      int dd0 = (idx & 7) * 8;
      const u16* gq = qkv + (rowbase + it * 32 + n) * CQ3 + colq + dd0;
      u16x8 q8 = *(const u16x8*)gq;
      u16x8 k8 = *(const u16x8*)(gq + C_DIM);
#pragma unroll
      for (int i = 0; i < 8; ++i) {
        float qf = bf2f(q8[i]); sq[i] += qf * qf;
        float kf = bf2f(k8[i]); sk[i] += kf * kf;
      }
      int base = ((n >> 3) * 64 + dd0) * 8 + (n & 7);   // transposed [nb2][d][nin]
#pragma unroll
      for (int i = 0; i < 8; ++i) {
        Qs[wid][base + i * 8] = q8[i];
        Ks[wid][base + i * 8] = k8[i];
      }
    }
    const int krow = lane >> 4;
    bf16x8 aq[4], ak[4];
#pragma unroll
    for (int m = 0; m < 4; ++m) {
      aq[m] = *(const bf16x8*)&Qs[wid][(krow * 64 + m * 16 + (lane & 15)) * 8];
      ak[m] = *(const bf16x8*)&Ks[wid][(krow * 64 + m * 16 + (lane & 15)) * 8];
    }
#pragma unroll
    for (int dm = 0; dm < 4; ++dm)
#pragma unroll
      for (int em = 0; em < 4; ++em)
        acc[dm][em] = __builtin_amdgcn_mfma_f32_16x16x32_bf16(aq[dm], ak[em], acc[dm][em], 0, 0, 0);
  }
#pragma unroll
  for (int dm = 0; dm < 4; ++dm)
#pragma unroll
    for (int em = 0; em < 4; ++em)
#pragma unroll
      for (int r = 0; r < 4; ++r)
        atomicAdd(&Ssh[(dm * 16 + (lane >> 4) * 4 + r) * 64 + em * 16 + (lane & 15)], acc[dm][em][r]);
#pragma unroll
  for (int i = 0; i < 8; ++i) {
    atomicAdd(&ssqsh[(lane & 7) * 8 + i], sq[i]);
    atomicAdd(&ssqsh[64 + (lane & 7) * 8 + i], sk[i]);
  }
  __syncthreads();
  float* sp = Sp + ((size_t)bh * 16 + nblk) * 4096;
  for (int i = tid; i < 4096; i += 256) sp[i] = Ssh[i];
  if (tid < 128) {
    int c = tid & 63;
    int off = (tid < 64) ? (colq + c) : (C_DIM + colq + c);
    atomicAdd(&ssq[b * 1024 + off], ssqsh[tid]);
  }
}

// ---------------- K3: softmax + fold into proj: M_b[c'=h*64+e][j] ----------------
__global__ __launch_bounds__(256) void k_attn_m(const float* __restrict__ Sp,
                                                const float* __restrict__ ssq,
                                                const float* __restrict__ temp,
                                                const float* __restrict__ pw,
                                                u16* __restrict__ Ml) {
  __shared__ float Ssh[4096];
  __shared__ float rq[64], rk[64];
  const int tid = threadIdx.x, lane = tid & 63, wid = tid >> 6;
  const int bh = blockIdx.x, b = bh >> 3, hh = bh & 7;
#pragma unroll
  for (int t2 = 0; t2 < 16; ++t2) {
    int idx = t2 * 256 + tid;
    float s = 0.f;
#pragma unroll
    for (int p = 0; p < 16; ++p) s += Sp[((size_t)bh * 16 + p) * 4096 + idx];
    Ssh[idx] = s;
  }
  if (tid < 64)
    rq[tid] = 1.f / fmaxf(sqrtf(ssq[b * 1024 + hh * 64 + tid]), 1e-12f);
  else if (tid < 128)
    rk[tid - 64] = 1.f / fmaxf(sqrtf(ssq[b * 1024 + C_DIM + hh * 64 + (tid - 64)]), 1e-12f);
  __syncthreads();
  const float tp = temp[hh];
  const int d = tid >> 2, q4 = tid & 3;
  float vals[16];
  float mx = -3.0e38f;
  const float rqd = rq[d];
#pragma unroll
  for (int i = 0; i < 16; ++i) {
    float v = Ssh[d * 64 + q4 * 16 + i] * rqd * rk[q4 * 16 + i] * tp;
    vals[i] = v; mx = fmaxf(mx, v);
  }
  mx = fmaxf(mx, __shfl_xor(mx, 1));
  mx = fmaxf(mx, __shfl_xor(mx, 2));
  float sum = 0.f;
#pragma unroll
  for (int i = 0; i < 16; ++i) { vals[i] = __expf(vals[i] - mx); sum += vals[i]; }
  sum += __shfl_xor(sum, 1);
  sum += __shfl_xor(sum, 2);
  const float inv = 1.f / sum;
#pragma unroll
  for (int i = 0; i < 16; ++i) Ssh[d * 64 + q4 * 16 + i] = vals[i] * inv;
  __syncthreads();
  f32x4 macc[4][8];
#pragma unroll
  for (int i = 0; i < 4; ++i)
#pragma unroll
    for (int j = 0; j < 8; ++j) macc[i][j] = (f32x4){0.f, 0.f, 0.f, 0.f};
#pragma unroll
  for (int kk = 0; kk < 2; ++kk) {
    bf16x8 af[4], bfr[8];
#pragma unroll
    for (int em = 0; em < 4; ++em) {
      u16x8 t8;
#pragma unroll
      for (int i = 0; i < 8; ++i) {
        int dd = kk * 32 + (lane >> 4) * 8 + i;
        t8[i] = f2bf(Ssh[dd * 64 + em * 16 + (lane & 15)]);
      }
      af[em] = as_bf16x8(t8);
    }
#pragma unroll
    for (int nt = 0; nt < 8; ++nt) {
      int j = wid * 128 + nt * 16 + (lane & 15);
      u16x8 t8;
#pragma unroll
      for (int i = 0; i < 8; ++i) {
        int dd = kk * 32 + (lane >> 4) * 8 + i;
        t8[i] = f2bf(pw[(size_t)(hh * 64 + dd) * C_DIM + j]);
      }
      bfr[nt] = as_bf16x8(t8);
    }
#pragma unroll
    for (int em = 0; em < 4; ++em)
#pragma unroll
      for (int nt = 0; nt < 8; ++nt)
        macc[em][nt] = __builtin_amdgcn_mfma_f32_16x16x32_bf16(af[em], bfr[nt], macc[em][nt], 0, 0, 0);
  }
#pragma unroll
  for (int em = 0; em < 4; ++em)
#pragma unroll
    for (int nt = 0; nt < 8; ++nt) {
      int j = wid * 128 + nt * 16 + (lane & 15);
#pragma unroll
      for (int r = 0; r < 4; ++r) {
        int e = em * 16 + (lane >> 4) * 4 + r;
        int cp = hh * 64 + e;
        Ml[(size_t)b * 262144 + ((size_t)(cp >> 3) * C_DIM + j) * 8 + (cp & 7)] = f2bf(macc[em][nt][r]);
      }
    }
}

extern "C" void kernel_launch(void* const* d_in, const int* in_sizes, int n_in,
                              void* d_out, int out_size, void* d_ws, size_t ws_size,
                              hipStream_t stream) {
  const float* x      = (const float*)d_in[0];
  const float* qkv_w  = (const float*)d_in[3];
  const float* proj_w = (const float*)d_in[4];
  const float* proj_b = (const float*)d_in[5];
  const float* temp   = (const float*)d_in[6];
  float* out = (float*)d_out;

  char* ws = (char*)d_ws;
  const size_t XB_B  = (size_t)NROWS * C_DIM * 2;      // 67108864
  const size_t QKV_B = (size_t)NROWS * CQ3 * 2;        // 201326592
  const size_t WL_B  = (size_t)C_DIM * CQ3 * 2;        // 1572864
  const size_t SP_B  = (size_t)32 * 16 * 4096 * 4;     // 8388608
  const size_t SSQ_B = (size_t)4096 * 4;               // 16384
  u16*   xb  = (u16*)ws;
  u16*   qkv = (u16*)(ws + XB_B);
  u16*   wl  = (u16*)(ws + XB_B + QKV_B);
  float* Sp  = (float*)(ws + XB_B + QKV_B + WL_B);
  float* ssq = (float*)(ws + XB_B + QKV_B + WL_B + SP_B);
  u16*   Ml  = (u16*)(ws + XB_B + QKV_B + WL_B + SP_B + SSQ_B);

  k_zero<<<16, 256, 0, stream>>>(ssq, 4096);
  k_wswz<<<384, 256, 0, stream>>>(qkv_w, wl);
  k_xb<<<2048, 256, 0, stream>>>(x, xb);
  k_qkv<<<1536, 512, 0, stream>>>(xb, wl, qkv);
  k_gram<<<dim3(16, 32), 256, 0, stream>>>(qkv, Sp, ssq);
  k_attn_m<<<32, 256, 0, stream>>>(Sp, ssq, temp, proj_w, Ml);
  k_out<<<512, 512, 0, stream>>>(qkv, Ml, proj_b, out);
}